// Round 5
// baseline (6612.536 us; speedup 1.0000x reference)
//
#include <hip/hip_runtime.h>
#include <cstdint>
#include <cstddef>

#define INP  40
#define HID  768
#define NG   3072      // 4*HID
#define NW   200       // windows
#define TS   160       // timesteps per window
#define GW   50        // windows per group
#define NS   64        // gate slices
#define SH   12        // h-dims per slice
#define SR   48        // gate rows per slice (4*SH)
#define GS   52        // gates LDS row stride (floats)

typedef __bf16 bf16x8 __attribute__((ext_vector_type(8)));
typedef float  f32x4  __attribute__((ext_vector_type(4)));
typedef unsigned long long u64;
typedef unsigned int u32;

__device__ __forceinline__ unsigned short f2bf(float f) {
    unsigned u = __builtin_bit_cast(unsigned, f);
    unsigned r = ((u >> 16) & 1u) + 0x7fffu;   // RNE
    return (unsigned short)((u + r) >> 16);
}
__device__ __forceinline__ float bf2f(unsigned short h) {
    unsigned u = ((unsigned)h) << 16;
    return __builtin_bit_cast(float, u);
}
__device__ __forceinline__ float sigm(float x) { return 1.f / (1.f + expf(-x)); }

__global__ void zero_cnt(int* __restrict__ c) {
    int gid = blockIdx.x * 256 + threadIdx.x;            // 6144 (3 layers x 4 groups x 512)
    c[gid] = 0;
}

// pre-pack W_ih layers 1,2 to bf16 in packed-slice row order: [layer][s*48+n][768]
__global__ void pack_wip(const float* __restrict__ w1, const float* __restrict__ w2,
                         unsigned short* __restrict__ dst) {
    int gid = blockIdx.x * 256 + threadIdx.x;            // 2*NG*HID
    int l = gid / (NG * HID);
    int rem = gid - l * (NG * HID);
    int p = rem / HID, k = rem - p * HID;
    int s = p / SR, n = p - s * SR;
    int orow = (n / SH) * HID + s * SH + (n % SH);
    const float* w = l ? w2 : w1;
    dst[gid] = f2bf(w[(size_t)orow * HID + k]);
}

// ---- tree barrier, ALL-RELAXED (no fences): correctness relies on
// __syncthreads() draining vmcnt(0) (bypass stores acked at L3) before arrival.
// layout per group (512 ints): sub[j] at j*32, root at 256, epoch at 288
__device__ __forceinline__ void group_barrier(int* base, int s, int t1) {
    __syncthreads();
    if (threadIdx.x == 0) {
        int old = __hip_atomic_fetch_add(base + (s & 7) * 32, 1,
                                         __ATOMIC_RELAXED, __HIP_MEMORY_SCOPE_AGENT);
        if (old == t1 * 8 - 1) {
            int ro = __hip_atomic_fetch_add(base + 256, 1,
                                            __ATOMIC_RELAXED, __HIP_MEMORY_SCOPE_AGENT);
            if (ro == t1 * 8 - 1)
                __hip_atomic_store(base + 288, t1, __ATOMIC_RELAXED, __HIP_MEMORY_SCOPE_AGENT);
        }
        while (__hip_atomic_load(base + 288, __ATOMIC_RELAXED, __HIP_MEMORY_SCOPE_AGENT) < t1)
            __builtin_amdgcn_s_sleep(2);
    }
    __syncthreads();
}

// ---------------- persistent recurrent scan ----------------
// grid 256 = 64 slices (s) x 4 groups (g); block 256 = 4 waves; wave v owns M-tile v.
// slice s owns h-dims [12s,12s+12): packed row n = chunk*12 + j <-> gate row chunk*768 + s*12 + j
// Per step: own-h staged LDS (uncached loads), W_hh in LDS, W_ih streamed from L2 (cached).
template <int LAYER>
__launch_bounds__(256, 1)
__global__ void lstm_scan(const float* __restrict__ whh,   // [3072][768] fp32
                          const float* __restrict__ wih,   // layer0: [3072][40] fp32
                          const unsigned short* __restrict__ wip, // layers1,2: packed bf16 [3072][768]
                          const float* __restrict__ b_ih,  // [3072]
                          const float* __restrict__ b_hh,  // [3072]
                          const unsigned short* __restrict__ prev, // prev-layer hist (layers 1,2)
                          const float* __restrict__ x,     // raw input (layer 0)
                          unsigned short* __restrict__ hist, // [TS+1][NW][HID] bf16
                          int* __restrict__ cnt)           // THIS LAYER's 4 groups x 512 ints
{
    __shared__ __align__(16) unsigned short Wh[SR * HID];   // 73728 B, swizzled
    __shared__ __align__(16) unsigned short hbuf[GW * HID]; // 76800 B, swizzled (own-h stage)
    __shared__ __align__(16) float gates[64 * GS];          // 13312 B   (total 163840 = 160 KiB)

    const int tid  = threadIdx.x;
    const int bid  = blockIdx.x;
    const int g    = bid & 3;
    const int s    = bid >> 2;
    const int v    = tid >> 6;
    const int lane = tid & 63;
    const int m    = lane & 15;
    const int kg   = lane >> 4;
    const int wl_f = v * 16 + m;                 // 0..63, valid < 50
    const int w_f  = GW * g + wl_f;
    const int w_c  = (w_f > NW - 1) ? (NW - 1) : w_f;   // clamped pad rows (discarded)
    const int arow = (wl_f < GW) ? wl_f : (GW - 1);     // clamped LDS A row
    const int aswz = arow & 7;
    int* barg = cnt + g * 512;

    // stage W_hh slice into LDS, fp32 -> bf16, XOR swizzle
    for (int idx = tid; idx < SR * (HID / 8); idx += 256) {
        int n = idx / (HID / 8), c8 = idx - n * (HID / 8);
        int orow = (n / SH) * HID + s * SH + (n % SH);
        const float* ph = whh + (size_t)orow * HID + c8 * 8;
        bf16x8 vh;
#pragma unroll
        for (int e = 0; e < 8; ++e) vh[e] = (__bf16)ph[e];
        *(bf16x8*)(&Wh[n * HID + ((c8 ^ (n & 7)) << 3)]) = vh;
    }

    // zero own part of hist slot 0 (h_{-1}=0), agent-bypass packed stores; c-state in regs
    float2 cA = {0.f, 0.f}, cB = {0.f, 0.f};
    for (int i = tid; i < GW * SH / 2; i += 256) {     // 300 u32 pairs
        int wl = i / (SH / 2), dp = i - wl * (SH / 2);
        u32* hp = (u32*)(hist + (size_t)(GW * g + wl) * HID + s * SH) + dp;
        __hip_atomic_store(hp, 0u, __ATOMIC_RELAXED, __HIP_MEMORY_SCOPE_AGENT);
    }

    // elementwise-phase biases (item p0 = tid, item p1 = tid+256 valid if tid<44)
    float bE0[4][2], bE1[4][2];
    {
        int dp0 = tid % (SH / 2);
        int h0 = s * SH + 2 * dp0;
#pragma unroll
        for (int c = 0; c < 4; ++c) {
            bE0[c][0] = b_ih[c * HID + h0] + b_hh[c * HID + h0];
            bE0[c][1] = b_ih[c * HID + h0 + 1] + b_hh[c * HID + h0 + 1];
        }
        if (tid < GW * SH / 2 - 256) {
            int dp1 = (tid + 256) % (SH / 2);
            int h1 = s * SH + 2 * dp1;
#pragma unroll
            for (int c = 0; c < 4; ++c) {
                bE1[c][0] = b_ih[c * HID + h1] + b_hh[c * HID + h1];
                bE1[c][1] = b_ih[c * HID + h1 + 1] + b_hh[c * HID + h1 + 1];
            }
        }
    }

    // layer-0: persistent W_ih fragments in registers (K = 40 padded to 64)
    bf16x8 bih[3][2];
    // layers 1,2: per-lane streamed W_ih fragment base pointers (packed bf16, L2-hot)
    const unsigned short* wfrag[3];
    if constexpr (LAYER == 0) {
#pragma unroll
        for (int nt = 0; nt < 3; ++nt) {
            int pl = nt * 16 + m;
            int orow = (pl / SH) * HID + s * SH + (pl % SH);
#pragma unroll
            for (int e = 0; e < 8; ++e) {
                int k0 = kg * 8 + e;
                int k1 = 32 + kg * 8 + e;
                bih[nt][0][e] = (k0 < INP) ? (__bf16)wih[(size_t)orow * INP + k0] : (__bf16)0.f;
                bih[nt][1][e] = (k1 < INP) ? (__bf16)wih[(size_t)orow * INP + k1] : (__bf16)0.f;
            }
        }
    } else {
#pragma unroll
        for (int nt = 0; nt < 3; ++nt)
            wfrag[nt] = wip + (size_t)(s * SR + nt * 16 + m) * HID + kg * 8;
    }

    group_barrier(barg, s, 1);

    // running pointers
    const u64* hq = (const u64*)(hist + (size_t)(GW * g) * HID);          // slot t, group base
    const unsigned short* pr = nullptr;
    if constexpr (LAYER != 0) pr = prev + ((size_t)NW + w_c) * HID + kg * 8; // slot t+1, own row
    const float* xr = x + (size_t)(80 * w_f) * INP;                        // layer 0
    unsigned short* hd = hist + ((size_t)NW + GW * g) * HID;               // slot t+1, group base

    for (int t = 0; t < TS; ++t) {
        // ---- A) issue own-h uncached loads (9600 u64 units, 38/thread, pipelined) ----
        u64 tmp[38];
#pragma unroll
        for (int j = 0; j < 37; ++j)
            tmp[j] = __hip_atomic_load(hq + tid + j * 256, __ATOMIC_RELAXED, __HIP_MEMORY_SCOPE_AGENT);
        if (tid < 128)
            tmp[37] = __hip_atomic_load(hq + tid + 37 * 256, __ATOMIC_RELAXED, __HIP_MEMORY_SCOPE_AGENT);

        f32x4 acc[3];
        const f32x4 zf = {0.f, 0.f, 0.f, 0.f};
#pragma unroll
        for (int nt = 0; nt < 3; ++nt) acc[nt] = zf;

        // ---- B) barrier-independent MFMA work (overlaps A's L3 latency) ----
        if constexpr (LAYER == 0) {
            bf16x8 ax0 = (bf16x8)(__bf16)0.f, ax1 = (bf16x8)(__bf16)0.f;
            if (wl_f < GW) {
                const float4* p0 = (const float4*)(xr + kg * 8);
                float4 u0 = p0[0], u1 = p0[1];
                ax0[0] = (__bf16)u0.x; ax0[1] = (__bf16)u0.y; ax0[2] = (__bf16)u0.z; ax0[3] = (__bf16)u0.w;
                ax0[4] = (__bf16)u1.x; ax0[5] = (__bf16)u1.y; ax0[6] = (__bf16)u1.z; ax0[7] = (__bf16)u1.w;
                if (kg == 0) {
                    const float4* p1 = (const float4*)(xr + 32);
                    float4 q0 = p1[0], q1 = p1[1];
                    ax1[0] = (__bf16)q0.x; ax1[1] = (__bf16)q0.y; ax1[2] = (__bf16)q0.z; ax1[3] = (__bf16)q0.w;
                    ax1[4] = (__bf16)q1.x; ax1[5] = (__bf16)q1.y; ax1[6] = (__bf16)q1.z; ax1[7] = (__bf16)q1.w;
                }
            }
#pragma unroll
            for (int nt = 0; nt < 3; ++nt) {
                acc[nt] = __builtin_amdgcn_mfma_f32_16x16x32_bf16(ax0, bih[nt][0], acc[nt], 0, 0, 0);
                acc[nt] = __builtin_amdgcn_mfma_f32_16x16x32_bf16(ax1, bih[nt][1], acc[nt], 0, 0, 0);
            }
        } else {
            // h_prev_layer(t) @ W_ih^T : A per-lane cached, B streamed from L2 (packed bf16)
#pragma unroll 4
            for (int kc = 0; kc < 24; ++kc) {
                bf16x8 a = *(const bf16x8*)(pr + kc * 32);
#pragma unroll
                for (int nt = 0; nt < 3; ++nt) {
                    bf16x8 b = *(const bf16x8*)(wfrag[nt] + kc * 32);
                    acc[nt] = __builtin_amdgcn_mfma_f32_16x16x32_bf16(a, b, acc[nt], 0, 0, 0);
                }
            }
        }

        // ---- C) write staged h into LDS (swizzled), then sync ----
#pragma unroll
        for (int j = 0; j < 37; ++j) {
            int u = tid + j * 256;
            int w = u / 192, jj = u - w * 192;
            int c8 = jj >> 1, half = jj & 1;
            ((u64*)hbuf)[w * 192 + ((c8 ^ (w & 7)) << 1) + half] = tmp[j];
        }
        if (tid < 128) {
            int u = tid + 37 * 256;
            int w = u / 192, jj = u - w * 192;
            int c8 = jj >> 1, half = jj & 1;
            ((u64*)hbuf)[w * 192 + ((c8 ^ (w & 7)) << 1) + half] = tmp[37];
        }
        __syncthreads();

        // ---- D) recurrent K-loop: A from hbuf (LDS), B from Wh (LDS) ----
#pragma unroll 4
        for (int kc = 0; kc < 24; ++kc) {
            int c8 = kc * 4 + kg;
            bf16x8 a = *(const bf16x8*)(&hbuf[arow * HID + ((c8 ^ aswz) << 3)]);
#pragma unroll
            for (int nt = 0; nt < 3; ++nt) {
                int n = nt * 16 + m;
                bf16x8 b = *(const bf16x8*)(&Wh[n * HID + ((c8 ^ (n & 7)) << 3)]);
                acc[nt] = __builtin_amdgcn_mfma_f32_16x16x32_bf16(a, b, acc[nt], 0, 0, 0);
            }
        }

        // ---- E) gates -> LDS (row = window, col = packed gate row) ----
#pragma unroll
        for (int nt = 0; nt < 3; ++nt) {
            int pl = nt * 16 + m;
#pragma unroll
            for (int r = 0; r < 4; ++r)
                gates[(v * 16 + kg * 4 + r) * GS + pl] = acc[nt][r];
        }
        __syncthreads();

        // ---- F) elementwise LSTM cell update (c in regs), bypass-store h ----
        {
            int wl = tid / (SH / 2), dp = tid - wl * (SH / 2);
            const float* gr = &gates[wl * GS + 2 * dp];
            float h01[2];
#pragma unroll
            for (int e = 0; e < 2; ++e) {
                float ig = gr[e]          + bE0[0][e];
                float fg = gr[SH + e]     + bE0[1][e];
                float gg = gr[2 * SH + e] + bE0[2][e];
                float og = gr[3 * SH + e] + bE0[3][e];
                float c = (e == 0) ? cA.x : cA.y;
                c = sigm(fg) * c + sigm(ig) * tanhf(gg);
                h01[e] = sigm(og) * tanhf(c);
                if (e == 0) cA.x = c; else cA.y = c;
            }
            u32 hv = (u32)f2bf(h01[0]) | ((u32)f2bf(h01[1]) << 16);
            u32* hp = (u32*)(hd + (size_t)wl * HID + s * SH) + dp;
            __hip_atomic_store(hp, hv, __ATOMIC_RELAXED, __HIP_MEMORY_SCOPE_AGENT);
        }
        if (tid < GW * SH / 2 - 256) {
            int p = tid + 256;
            int wl = p / (SH / 2), dp = p - wl * (SH / 2);
            const float* gr = &gates[wl * GS + 2 * dp];
            float h01[2];
#pragma unroll
            for (int e = 0; e < 2; ++e) {
                float ig = gr[e]          + bE1[0][e];
                float fg = gr[SH + e]     + bE1[1][e];
                float gg = gr[2 * SH + e] + bE1[2][e];
                float og = gr[3 * SH + e] + bE1[3][e];
                float c = (e == 0) ? cB.x : cB.y;
                c = sigm(fg) * c + sigm(ig) * tanhf(gg);
                h01[e] = sigm(og) * tanhf(c);
                if (e == 0) cB.x = c; else cB.y = c;
            }
            u32 hv = (u32)f2bf(h01[0]) | ((u32)f2bf(h01[1]) << 16);
            u32* hp = (u32*)(hd + (size_t)wl * HID + s * SH) + dp;
            __hip_atomic_store(hp, hv, __ATOMIC_RELAXED, __HIP_MEMORY_SCOPE_AGENT);
        }

        // advance running pointers
        hq += (size_t)NW * HID / 4;
        hd += (size_t)NW * HID;
        if constexpr (LAYER != 0) pr += (size_t)NW * HID;
        else                      xr += INP;

        if (t != TS - 1) group_barrier(barg, s, t + 2);
    }
}

// ---------------- output head ----------------
__global__ void out_y(const unsigned short* __restrict__ hist, const float* __restrict__ wout,
                      const float* __restrict__ bout, float* __restrict__ yn) {
    __shared__ float hv[HID];
    __shared__ float red[256];
    const int w = blockIdx.x, tid = threadIdx.x;
    const u32* hrow = (const u32*)(hist + ((size_t)TS * NW + w) * HID);
    for (int i = tid; i < HID / 2; i += 256) {
        u32 u = __hip_atomic_load(hrow + i, __ATOMIC_RELAXED, __HIP_MEMORY_SCOPE_AGENT);
        hv[2 * i]     = bf2f((unsigned short)(u & 0xffffu));
        hv[2 * i + 1] = bf2f((unsigned short)(u >> 16));
    }
    __syncthreads();
    float acc = bout[tid];
    const float* wr = wout + (size_t)tid * HID;
    for (int k = 0; k < HID; ++k) acc += hv[k] * wr[k];
    red[tid] = acc * acc;
    __syncthreads();
    for (int off = 128; off > 0; off >>= 1) {
        if (tid < off) red[tid] += red[tid + off];
        __syncthreads();
    }
    float inv = 1.f / sqrtf(red[0]);
    yn[w * 256 + tid] = acc * inv;
}

__global__ void out_reduce(const float* __restrict__ yn, float* __restrict__ out) {
    const int o = threadIdx.x;
    float s = 0.f;
    for (int w = 0; w < NW; ++w) s += yn[w * 256 + o];
    out[o] = s * (1.f / NW);
}

// ---------------- host ----------------
extern "C" void kernel_launch(void* const* d_in, const int* in_sizes, int n_in,
                              void* d_out, int out_size, void* d_ws, size_t ws_size,
                              hipStream_t stream) {
    (void)in_sizes; (void)n_in; (void)out_size;
    const float* x    = (const float*)d_in[0];
    const float* wih0 = (const float*)d_in[1];
    const float* whh0 = (const float*)d_in[2];
    const float* bi0  = (const float*)d_in[3];
    const float* bh0  = (const float*)d_in[4];
    const float* wih1 = (const float*)d_in[5];
    const float* whh1 = (const float*)d_in[6];
    const float* bi1  = (const float*)d_in[7];
    const float* bh1  = (const float*)d_in[8];
    const float* wih2 = (const float*)d_in[9];
    const float* whh2 = (const float*)d_in[10];
    const float* bi2  = (const float*)d_in[11];
    const float* bh2  = (const float*)d_in[12];
    const float* wout = (const float*)d_in[13];
    const float* bout = (const float*)d_in[14];

    char* base = (char*)d_ws;
    size_t off = 0;
    auto take = [&](size_t bytes) { size_t r = off; off += (bytes + 255) & ~(size_t)255; return r; };
    unsigned short* HA  = (unsigned short*)(base + take((size_t)(TS + 1) * NW * HID * 2)); // 49.5 MB
    unsigned short* HB  = (unsigned short*)(base + take((size_t)(TS + 1) * NW * HID * 2)); // 49.5 MB
    unsigned short* WIP = (unsigned short*)(base + take(2UL * NG * HID * 2));              // 9.4 MB
    int*            CNT = (int*)(base + take(3UL * 2048 * 4));   // per-layer barrier regions
    float*          YN  = (float*)(base + take((size_t)NW * 256 * 4));
    if (ws_size < off) return;  // ~109 MB needed; leave d_out zeroed (visible failure)

    zero_cnt<<<dim3(24), dim3(256), 0, stream>>>(CNT);
    pack_wip<<<dim3(18432), dim3(256), 0, stream>>>(wih1, wih2, WIP);

    lstm_scan<0><<<dim3(256), dim3(256), 0, stream>>>(whh0, wih0, nullptr, bi0, bh0,
                                                      nullptr, x, HA, CNT);
    lstm_scan<1><<<dim3(256), dim3(256), 0, stream>>>(whh1, nullptr, WIP, bi1, bh1,
                                                      HA, nullptr, HB, CNT + 2048);
    lstm_scan<2><<<dim3(256), dim3(256), 0, stream>>>(whh2, nullptr, WIP + (size_t)NG * HID,
                                                      bi2, bh2, HB, nullptr, HA, CNT + 4096);

    out_y<<<dim3(NW), dim3(256), 0, stream>>>(HA, wout, bout, YN);
    out_reduce<<<dim3(1), dim3(256), 0, stream>>>(YN, (float*)d_out);
}

// Round 6
// 6378.153 us; speedup vs baseline: 1.0367x; 1.0367x over previous
//
#include <hip/hip_runtime.h>
#include <cstdint>
#include <cstddef>

#define INP  40
#define HID  768
#define NW   200       // windows
#define TS   160       // timesteps per window
#define GW   50        // windows per group
#define SH   12        // h-dims per slice
#define SR   48        // gate rows per slice (4*SH)
#define GS   52        // gates LDS row stride (floats)

typedef __bf16 bf16x8 __attribute__((ext_vector_type(8)));
typedef float  f32x4  __attribute__((ext_vector_type(4)));
typedef unsigned long long u64;
typedef unsigned int u32;
typedef unsigned short u16;

__device__ __forceinline__ u16 f2bf(float f) {
    unsigned u = __builtin_bit_cast(unsigned, f);
    unsigned r = ((u >> 16) & 1u) + 0x7fffu;   // RNE
    return (u16)((u + r) >> 16);
}
__device__ __forceinline__ float bf2f(u16 h) {
    unsigned u = ((unsigned)h) << 16;
    return __builtin_bit_cast(float, u);
}
__device__ __forceinline__ float sigm(float x) { return 1.f / (1.f + expf(-x)); }

__global__ void zero_flags(int* __restrict__ c) {
    c[blockIdx.x * 256 + threadIdx.x] = 0;               // 768 = 3 layers x 4 groups x 64
}

// ---- flat flag barrier: arrival = relaxed store flg[s]=epoch;
// detect = wave0 vector-loads all 64 flags (one global_load) + __all.
// Ordering: __syncthreads() drains every wave's vmcnt (bypass h-stores acked)
// before thread0 publishes the flag. Validated chain (R5 numerics).
__device__ __forceinline__ void flag_barrier(int* flg, int s, int epoch) {
    __syncthreads();
    const int tid = threadIdx.x;
    if (tid == 0)
        __hip_atomic_store(flg + s, epoch, __ATOMIC_RELAXED, __HIP_MEMORY_SCOPE_AGENT);
    if (tid < 64) {
        while (!__all(__hip_atomic_load(flg + tid, __ATOMIC_RELAXED,
                                        __HIP_MEMORY_SCOPE_AGENT) >= epoch))
            __builtin_amdgcn_s_sleep(1);
    }
    __syncthreads();
}

// ---------------- persistent recurrent scan ----------------
// grid 256 = 64 slices (s) x 4 groups (g); block 256 = 4 waves; wave v owns M-tile v
// (windows 16v..16v+15 of the group, valid < 50) and all 48 gate cols.
// slice s owns h-dims [12s,12s+12): packed row n = chunk*12 + j <-> gate row chunk*768 + s*12 + j
template <int LAYER>
__launch_bounds__(256, 1)
__global__ void lstm_scan(const float* __restrict__ whh,   // [3072][768] fp32
                          const float* __restrict__ wih,   // [3072][768] fp32 (layer0: [3072][40])
                          const float* __restrict__ b_ih,  // [3072]
                          const float* __restrict__ b_hh,  // [3072]
                          const u16* __restrict__ prev,    // prev-layer hist (layers 1,2)
                          const float* __restrict__ x,     // raw input (layer 0)
                          u16* __restrict__ hist,          // [TS+1][NW][HID] bf16
                          int* __restrict__ flags)         // this layer's 4 groups x 64 ints
{
    __shared__ __align__(16) u16 Wh[SR * HID];   // 73728 B, swizzled
    __shared__ __align__(16) u16 Wi[SR * HID];   // 73728 B (unused for layer 0)
    __shared__ __align__(16) float gates[64 * GS]; // 13312 B  (total 160768 <= 163840)

    const int tid  = threadIdx.x;
    const int bid  = blockIdx.x;
    const int g    = bid & 3;
    const int s    = bid >> 2;
    const int v    = tid >> 6;
    const int lane = tid & 63;
    const int m    = lane & 15;
    const int kg   = lane >> 4;
    const int wl_f = v * 16 + m;                 // MFMA A row in group, valid < 50
    const int w_f  = GW * g + wl_f;
    const int w_c  = (w_f > NW - 1) ? (NW - 1) : w_f;   // clamped pad rows (discarded)
    int* flg = flags + g * 64;

    // ---- stage W_hh (+W_ih) slice into LDS, fp32 -> bf16, XOR swizzle ----
    for (int idx = tid; idx < SR * (HID / 8); idx += 256) {
        int n = idx / (HID / 8), c8 = idx - n * (HID / 8);
        int orow = (n / SH) * HID + s * SH + (n % SH);
        const float* ph = whh + (size_t)orow * HID + c8 * 8;
        bf16x8 vh;
#pragma unroll
        for (int e = 0; e < 8; ++e) vh[e] = (__bf16)ph[e];
        *(bf16x8*)(&Wh[n * HID + ((c8 ^ (n & 7)) << 3)]) = vh;
        if constexpr (LAYER != 0) {
            const float* pi = wih + (size_t)orow * HID + c8 * 8;
            bf16x8 vi;
#pragma unroll
            for (int e = 0; e < 8; ++e) vi[e] = (__bf16)pi[e];
            *(bf16x8*)(&Wi[n * HID + ((c8 ^ (n & 7)) << 3)]) = vi;
        }
    }

    // ---- elementwise-lane ownership: window w_l, dims db..db+2 ----
    const int w_l = v * 16 + (lane >> 2);        // 0..63, valid < 50
    const int db  = (lane & 3) * 3;              // 0,3,6,9
    const bool fvalid = (w_l < GW);
    float bF[4][3];
#pragma unroll
    for (int c = 0; c < 4; ++c)
#pragma unroll
        for (int e = 0; e < 3; ++e)
            bF[c][e] = b_ih[c * HID + s * SH + db + e] + b_hh[c * HID + s * SH + db + e];
    float cs[3] = {0.f, 0.f, 0.f};

    // zero own part of hist slot 0 (h_{-1} = 0), bypass stores
    if (fvalid) {
        u16* h0 = hist + (size_t)(GW * g + w_l) * HID + s * SH + db;
#pragma unroll
        for (int e = 0; e < 3; ++e)
            __hip_atomic_store(h0 + e, (u16)0, __ATOMIC_RELAXED, __HIP_MEMORY_SCOPE_AGENT);
    }

    // layer-0: persistent W_ih fragments in registers (K = 40 padded to 64)
    bf16x8 bih[3][2];
    if constexpr (LAYER == 0) {
#pragma unroll
        for (int nt = 0; nt < 3; ++nt) {
            int pl = nt * 16 + m;
            int orow = (pl / SH) * HID + s * SH + (pl % SH);
#pragma unroll
            for (int e = 0; e < 8; ++e) {
                int k0 = kg * 8 + e;
                int k1 = 32 + kg * 8 + e;
                bih[nt][0][e] = (k0 < INP) ? (__bf16)wih[(size_t)orow * INP + k0] : (__bf16)0.f;
                bih[nt][1][e] = (k1 < INP) ? (__bf16)wih[(size_t)orow * INP + k1] : (__bf16)0.f;
            }
        }
    }

    flag_barrier(flg, s, 1);

    // prev-layer A-frag prefetch (slot t+1 = 1), cached loads (immutable this dispatch)
    bf16x8 pf[24];
    if constexpr (LAYER != 0) {
        const u16* pr = prev + ((size_t)NW + w_c) * HID + kg * 8;
#pragma unroll
        for (int kc = 0; kc < 24; ++kc) pf[kc] = *(const bf16x8*)(pr + kc * 32);
    }
    const float* xr = x + (size_t)(80 * w_f) * INP;   // layer 0

    union UA { u64 q[2]; bf16x8 v; };

    for (int t = 0; t < TS; ++t) {
        // ---- A) batched bypass loads of own-h (48 u64 in flight, reg-resident) ----
        u64 tA[48];
        const u64* hq = (const u64*)hist + ((size_t)t * NW + w_c) * (HID / 4);
#pragma unroll
        for (int kc = 0; kc < 24; ++kc) {
            tA[2 * kc]     = __hip_atomic_load(hq + kc * 8 + kg * 2,
                                               __ATOMIC_RELAXED, __HIP_MEMORY_SCOPE_AGENT);
            tA[2 * kc + 1] = __hip_atomic_load(hq + kc * 8 + kg * 2 + 1,
                                               __ATOMIC_RELAXED, __HIP_MEMORY_SCOPE_AGENT);
        }

        f32x4 acc[3];
        const f32x4 zf = {0.f, 0.f, 0.f, 0.f};
#pragma unroll
        for (int nt = 0; nt < 3; ++nt) acc[nt] = zf;

        // ---- B) barrier-independent projection (overlaps A's L3 latency) ----
        if constexpr (LAYER == 0) {
            bf16x8 ax0 = (bf16x8)(__bf16)0.f, ax1 = (bf16x8)(__bf16)0.f;
            if (wl_f < GW) {
                const float4* p0 = (const float4*)(xr + kg * 8);
                float4 u0 = p0[0], u1 = p0[1];
                ax0[0] = (__bf16)u0.x; ax0[1] = (__bf16)u0.y; ax0[2] = (__bf16)u0.z; ax0[3] = (__bf16)u0.w;
                ax0[4] = (__bf16)u1.x; ax0[5] = (__bf16)u1.y; ax0[6] = (__bf16)u1.z; ax0[7] = (__bf16)u1.w;
                if (kg == 0) {
                    const float4* p1 = (const float4*)(xr + 32);
                    float4 q0 = p1[0], q1 = p1[1];
                    ax1[0] = (__bf16)q0.x; ax1[1] = (__bf16)q0.y; ax1[2] = (__bf16)q0.z; ax1[3] = (__bf16)q0.w;
                    ax1[4] = (__bf16)q1.x; ax1[5] = (__bf16)q1.y; ax1[6] = (__bf16)q1.z; ax1[7] = (__bf16)q1.w;
                }
            }
#pragma unroll
            for (int nt = 0; nt < 3; ++nt) {
                acc[nt] = __builtin_amdgcn_mfma_f32_16x16x32_bf16(ax0, bih[nt][0], acc[nt], 0, 0, 0);
                acc[nt] = __builtin_amdgcn_mfma_f32_16x16x32_bf16(ax1, bih[nt][1], acc[nt], 0, 0, 0);
            }
            xr += INP;
        } else {
            // h_prev_layer(t) @ W_ih^T from prefetched regs + LDS Wi
#pragma unroll
            for (int kc = 0; kc < 24; ++kc) {
                int c8 = kc * 4 + kg;
#pragma unroll
                for (int nt = 0; nt < 3; ++nt) {
                    int n = nt * 16 + m;
                    bf16x8 b = *(const bf16x8*)(&Wi[n * HID + ((c8 ^ (n & 7)) << 3)]);
                    acc[nt] = __builtin_amdgcn_mfma_f32_16x16x32_bf16(pf[kc], b, acc[nt], 0, 0, 0);
                }
            }
            // prefetch next step's prev frags (slot t+2, immutable, cached)
            if (t != TS - 1) {
                const u16* pn = prev + ((size_t)(t + 2) * NW + w_c) * HID + kg * 8;
#pragma unroll
                for (int kc = 0; kc < 24; ++kc) pf[kc] = *(const bf16x8*)(pn + kc * 32);
            }
        }

        // ---- D) recurrent K-loop: A from regs (tA), B from LDS Wh ----
#pragma unroll
        for (int kc = 0; kc < 24; ++kc) {
            UA ua; ua.q[0] = tA[2 * kc]; ua.q[1] = tA[2 * kc + 1];
            int c8 = kc * 4 + kg;
#pragma unroll
            for (int nt = 0; nt < 3; ++nt) {
                int n = nt * 16 + m;
                bf16x8 b = *(const bf16x8*)(&Wh[n * HID + ((c8 ^ (n & 7)) << 3)]);
                acc[nt] = __builtin_amdgcn_mfma_f32_16x16x32_bf16(ua.v, b, acc[nt], 0, 0, 0);
            }
        }

        // ---- E) gates -> wave-private LDS tile (no block sync needed) ----
#pragma unroll
        for (int nt = 0; nt < 3; ++nt) {
            int pl = nt * 16 + m;
#pragma unroll
            for (int r = 0; r < 4; ++r)
                gates[(v * 16 + kg * 4 + r) * GS + pl] = acc[nt][r];
        }

        // ---- F) wave-local LSTM cell update (lane owns window w_l, dims db..db+2) ----
        {
            const float* gr = &gates[w_l * GS + db];
            float hv[3];
#pragma unroll
            for (int e = 0; e < 3; ++e) {
                float ig = gr[e]          + bF[0][e];
                float fg = gr[SH + e]     + bF[1][e];
                float gg = gr[2 * SH + e] + bF[2][e];
                float og = gr[3 * SH + e] + bF[3][e];
                float c = sigm(fg) * cs[e] + sigm(ig) * tanhf(gg);
                cs[e] = c;
                hv[e] = sigm(og) * tanhf(c);
            }
            if (fvalid) {
                u16* hd = hist + ((size_t)(t + 1) * NW + GW * g + w_l) * HID + s * SH + db;
#pragma unroll
                for (int e = 0; e < 3; ++e)
                    __hip_atomic_store(hd + e, f2bf(hv[e]),
                                       __ATOMIC_RELAXED, __HIP_MEMORY_SCOPE_AGENT);
            }
        }

        if (t != TS - 1) flag_barrier(flg, s, t + 2);
    }
}

// ---------------- output head ----------------
__global__ void out_y(const u16* __restrict__ hist, const float* __restrict__ wout,
                      const float* __restrict__ bout, float* __restrict__ yn) {
    __shared__ float hv[HID];
    __shared__ float red[256];
    const int w = blockIdx.x, tid = threadIdx.x;
    for (int i = tid; i < HID; i += 256)
        hv[i] = bf2f(hist[((size_t)TS * NW + w) * HID + i]);
    __syncthreads();
    float acc = bout[tid];
    const float* wr = wout + (size_t)tid * HID;
    for (int k = 0; k < HID; ++k) acc += hv[k] * wr[k];
    red[tid] = acc * acc;
    __syncthreads();
    for (int off = 128; off > 0; off >>= 1) {
        if (tid < off) red[tid] += red[tid + off];
        __syncthreads();
    }
    float inv = 1.f / sqrtf(red[0]);
    yn[w * 256 + tid] = acc * inv;
}

__global__ void out_reduce(const float* __restrict__ yn, float* __restrict__ out) {
    const int o = threadIdx.x;
    float s = 0.f;
    for (int w = 0; w < NW; ++w) s += yn[w * 256 + o];
    out[o] = s * (1.f / NW);
}

// ---------------- host ----------------
extern "C" void kernel_launch(void* const* d_in, const int* in_sizes, int n_in,
                              void* d_out, int out_size, void* d_ws, size_t ws_size,
                              hipStream_t stream) {
    (void)in_sizes; (void)n_in; (void)out_size;
    const float* x    = (const float*)d_in[0];
    const float* wih0 = (const float*)d_in[1];
    const float* whh0 = (const float*)d_in[2];
    const float* bi0  = (const float*)d_in[3];
    const float* bh0  = (const float*)d_in[4];
    const float* wih1 = (const float*)d_in[5];
    const float* whh1 = (const float*)d_in[6];
    const float* bi1  = (const float*)d_in[7];
    const float* bh1  = (const float*)d_in[8];
    const float* wih2 = (const float*)d_in[9];
    const float* whh2 = (const float*)d_in[10];
    const float* bi2  = (const float*)d_in[11];
    const float* bh2  = (const float*)d_in[12];
    const float* wout = (const float*)d_in[13];
    const float* bout = (const float*)d_in[14];

    char* base = (char*)d_ws;
    size_t off = 0;
    auto take = [&](size_t bytes) { size_t r = off; off += (bytes + 255) & ~(size_t)255; return r; };
    u16*   HA  = (u16*)(base + take((size_t)(TS + 1) * NW * HID * 2)); // 49.5 MB
    u16*   HB  = (u16*)(base + take((size_t)(TS + 1) * NW * HID * 2)); // 49.5 MB
    int*   FLG = (int*)(base + take(768UL * 4));   // 3 layers x 4 groups x 64 flags
    float* YN  = (float*)(base + take((size_t)NW * 256 * 4));
    if (ws_size < off) return;  // ~99 MB needed; leave d_out zeroed (visible failure)

    zero_flags<<<dim3(3), dim3(256), 0, stream>>>(FLG);

    lstm_scan<0><<<dim3(256), dim3(256), 0, stream>>>(whh0, wih0, bi0, bh0, nullptr, x, HA, FLG);
    lstm_scan<1><<<dim3(256), dim3(256), 0, stream>>>(whh1, wih1, bi1, bh1, HA, nullptr, HB, FLG + 256);
    lstm_scan<2><<<dim3(256), dim3(256), 0, stream>>>(whh2, wih2, bi2, bh2, HB, nullptr, HA, FLG + 512);

    out_y<<<dim3(NW), dim3(256), 0, stream>>>(HA, wout, bout, YN);
    out_reduce<<<dim3(1), dim3(256), 0, stream>>>(YN, (float*)d_out);
}

// Round 7
// 5242.216 us; speedup vs baseline: 1.2614x; 1.2167x over previous
//
#include <hip/hip_runtime.h>
#include <cstdint>
#include <cstddef>

#define INP  40
#define HID  768
#define NW   200       // windows
#define TS   160       // timesteps per window
#define GW   50        // windows per group
#define SH   12        // h-dims per slice
#define SR   48        // gate rows per slice (4*SH)
#define GS   52        // gates LDS row stride (floats)

typedef __bf16 bf16x8 __attribute__((ext_vector_type(8)));
typedef float  f32x4  __attribute__((ext_vector_type(4)));
typedef unsigned long long u64;
typedef unsigned int u32;
typedef unsigned short u16;

__device__ __forceinline__ u16 f2bf(float f) {
    unsigned u = __builtin_bit_cast(unsigned, f);
    unsigned r = ((u >> 16) & 1u) + 0x7fffu;   // RNE
    return (u16)((u + r) >> 16);
}
__device__ __forceinline__ float bf2f(u16 h) {
    unsigned u = ((unsigned)h) << 16;
    return __builtin_bit_cast(float, u);
}
__device__ __forceinline__ float sigm(float x) { return 1.f / (1.f + expf(-x)); }

__global__ void zero_flags(int* __restrict__ c) {
    c[blockIdx.x * 256 + threadIdx.x] = 0;               // 768 = 3 layers x 4 groups x 64
}

// ---- flat flag barrier: arrival = relaxed agent store flg[s]=epoch;
// detect = wave0 loads all 64 flags (atomic/bypass, one coalesced global_load) + __all.
// Ordering: __syncthreads() drains every wave's vmcnt (bypass h-stores acked at L3)
// before thread0 publishes the flag.
__device__ __forceinline__ void flag_barrier(int* flg, int s, int epoch) {
    __syncthreads();
    const int tid = threadIdx.x;
    if (tid == 0)
        __hip_atomic_store(flg + s, epoch, __ATOMIC_RELAXED, __HIP_MEMORY_SCOPE_AGENT);
    if (tid < 64) {
        while (!__all(__hip_atomic_load(flg + tid, __ATOMIC_RELAXED,
                                        __HIP_MEMORY_SCOPE_AGENT) >= epoch))
            __builtin_amdgcn_s_sleep(1);
    }
    __syncthreads();
}

// ---------------- persistent recurrent scan ----------------
// grid 256 = 64 slices (s) x 4 groups (g); block 256 = 4 waves; wave v owns M-tile v
// (windows 16v..16v+15 of the group, valid < 50) and all 48 gate cols.
// slice s owns h-dims [12s,12s+12): packed row n = chunk*12 + j <-> gate row chunk*768 + s*12 + j
// h exchange: bypass stores (write-through to L3) + PLAIN cached loads post-barrier
// (safe: each hist address written once per dispatch, read only after the ordering
// barrier, and pad lanes clamp GROUP-LOCALLY so no line is touched before its write).
template <int LAYER>
__launch_bounds__(256, 1)
__global__ void lstm_scan(const float* __restrict__ whh,   // [3072][768] fp32
                          const float* __restrict__ wih,   // [3072][768] fp32 (layer0: [3072][40])
                          const float* __restrict__ b_ih,  // [3072]
                          const float* __restrict__ b_hh,  // [3072]
                          const u16* __restrict__ prev,    // prev-layer hist (layers 1,2)
                          const float* __restrict__ x,     // raw input (layer 0)
                          u16* __restrict__ hist,          // [TS+1][NW][HID] bf16
                          int* __restrict__ flags)         // this layer's 4 groups x 64 ints
{
    __shared__ __align__(16) u16 Wh[SR * HID];   // 73728 B, swizzled
    __shared__ __align__(16) u16 Wi[SR * HID];   // 73728 B (unused for layer 0)
    __shared__ __align__(16) float gates[64 * GS]; // 13312 B  (total 160768 <= 163840)

    const int tid  = threadIdx.x;
    const int bid  = blockIdx.x;
    const int g    = bid & 3;
    const int s    = bid >> 2;
    const int v    = tid >> 6;
    const int lane = tid & 63;
    const int m    = lane & 15;
    const int kg   = lane >> 4;
    const int wl_f = v * 16 + m;                         // MFMA A row in group, valid < 50
    const int w_f  = GW * g + wl_f;
    const int w_cl = GW * g + ((wl_f < GW) ? wl_f : (GW - 1)); // GROUP-LOCAL clamp
    int* flg = flags + g * 64;

    // ---- stage W_hh (+W_ih) slice into LDS, fp32 -> bf16, XOR swizzle ----
    for (int idx = tid; idx < SR * (HID / 8); idx += 256) {
        int n = idx / (HID / 8), c8 = idx - n * (HID / 8);
        int orow = (n / SH) * HID + s * SH + (n % SH);
        const float* ph = whh + (size_t)orow * HID + c8 * 8;
        bf16x8 vh;
#pragma unroll
        for (int e = 0; e < 8; ++e) vh[e] = (__bf16)ph[e];
        *(bf16x8*)(&Wh[n * HID + ((c8 ^ (n & 7)) << 3)]) = vh;
        if constexpr (LAYER != 0) {
            const float* pi = wih + (size_t)orow * HID + c8 * 8;
            bf16x8 vi;
#pragma unroll
            for (int e = 0; e < 8; ++e) vi[e] = (__bf16)pi[e];
            *(bf16x8*)(&Wi[n * HID + ((c8 ^ (n & 7)) << 3)]) = vi;
        }
    }

    // ---- elementwise-lane ownership: window w_l, dims db..db+2 ----
    const int w_l = v * 16 + (lane >> 2);        // 0..63, valid < 50
    const int db  = (lane & 3) * 3;              // 0,3,6,9
    const bool fvalid = (w_l < GW);
    float bF[4][3];
#pragma unroll
    for (int c = 0; c < 4; ++c)
#pragma unroll
        for (int e = 0; e < 3; ++e)
            bF[c][e] = b_ih[c * HID + s * SH + db + e] + b_hh[c * HID + s * SH + db + e];
    float cs[3] = {0.f, 0.f, 0.f};

    // zero own part of hist slot 0 (h_{-1} = 0), bypass stores
    if (fvalid) {
        u16* h0 = hist + (size_t)(GW * g + w_l) * HID + s * SH + db;
#pragma unroll
        for (int e = 0; e < 3; ++e)
            __hip_atomic_store(h0 + e, (u16)0, __ATOMIC_RELAXED, __HIP_MEMORY_SCOPE_AGENT);
    }

    // layer-0: persistent W_ih fragments in registers (K = 40 padded to 64)
    bf16x8 bih[3][2];
    if constexpr (LAYER == 0) {
#pragma unroll
        for (int nt = 0; nt < 3; ++nt) {
            int pl = nt * 16 + m;
            int orow = (pl / SH) * HID + s * SH + (pl % SH);
#pragma unroll
            for (int e = 0; e < 8; ++e) {
                int k0 = kg * 8 + e;
                int k1 = 32 + kg * 8 + e;
                bih[nt][0][e] = (k0 < INP) ? (__bf16)wih[(size_t)orow * INP + k0] : (__bf16)0.f;
                bih[nt][1][e] = (k1 < INP) ? (__bf16)wih[(size_t)orow * INP + k1] : (__bf16)0.f;
            }
        }
    }

    flag_barrier(flg, s, 1);

    // prev-layer A-frag prefetch (slot t+1 = 1), cached loads (immutable this dispatch)
    bf16x8 pf[24];
    if constexpr (LAYER != 0) {
        const u16* pr = prev + ((size_t)NW + w_cl) * HID + kg * 8;
#pragma unroll
        for (int kc = 0; kc < 24; ++kc) pf[kc] = *(const bf16x8*)(pr + kc * 32);
    }
    const float* xr = x + (size_t)(80 * w_f) * INP;   // layer 0

    for (int t = 0; t < TS; ++t) {
        // ---- A) PLAIN cached loads of own-h row (compiler pipelines freely;
        //         lines shared across the XCD's WGs via L2) ----
        bf16x8 tA[24];
        const u16* hrow = hist + ((size_t)t * NW + w_cl) * HID + kg * 8;
#pragma unroll
        for (int kc = 0; kc < 24; ++kc)
            tA[kc] = *(const bf16x8*)(hrow + kc * 32);

        f32x4 acc[3];
        const f32x4 zf = {0.f, 0.f, 0.f, 0.f};
#pragma unroll
        for (int nt = 0; nt < 3; ++nt) acc[nt] = zf;

        // ---- B) barrier-independent projection (overlaps A's latency) ----
        if constexpr (LAYER == 0) {
            bf16x8 ax0 = (bf16x8)(__bf16)0.f, ax1 = (bf16x8)(__bf16)0.f;
            if (wl_f < GW) {
                const float4* p0 = (const float4*)(xr + kg * 8);
                float4 u0 = p0[0], u1 = p0[1];
                ax0[0] = (__bf16)u0.x; ax0[1] = (__bf16)u0.y; ax0[2] = (__bf16)u0.z; ax0[3] = (__bf16)u0.w;
                ax0[4] = (__bf16)u1.x; ax0[5] = (__bf16)u1.y; ax0[6] = (__bf16)u1.z; ax0[7] = (__bf16)u1.w;
                if (kg == 0) {
                    const float4* p1 = (const float4*)(xr + 32);
                    float4 q0 = p1[0], q1 = p1[1];
                    ax1[0] = (__bf16)q0.x; ax1[1] = (__bf16)q0.y; ax1[2] = (__bf16)q0.z; ax1[3] = (__bf16)q0.w;
                    ax1[4] = (__bf16)q1.x; ax1[5] = (__bf16)q1.y; ax1[6] = (__bf16)q1.z; ax1[7] = (__bf16)q1.w;
                }
            }
#pragma unroll
            for (int nt = 0; nt < 3; ++nt) {
                acc[nt] = __builtin_amdgcn_mfma_f32_16x16x32_bf16(ax0, bih[nt][0], acc[nt], 0, 0, 0);
                acc[nt] = __builtin_amdgcn_mfma_f32_16x16x32_bf16(ax1, bih[nt][1], acc[nt], 0, 0, 0);
            }
            xr += INP;
        } else {
            // h_prev_layer(t) @ W_ih^T from prefetched regs + LDS Wi
#pragma unroll
            for (int kc = 0; kc < 24; ++kc) {
                int c8 = kc * 4 + kg;
#pragma unroll
                for (int nt = 0; nt < 3; ++nt) {
                    int n = nt * 16 + m;
                    bf16x8 b = *(const bf16x8*)(&Wi[n * HID + ((c8 ^ (n & 7)) << 3)]);
                    acc[nt] = __builtin_amdgcn_mfma_f32_16x16x32_bf16(pf[kc], b, acc[nt], 0, 0, 0);
                }
            }
            // prefetch next step's prev frags (slot t+2, immutable, cached)
            if (t != TS - 1) {
                const u16* pn = prev + ((size_t)(t + 2) * NW + w_cl) * HID + kg * 8;
#pragma unroll
                for (int kc = 0; kc < 24; ++kc) pf[kc] = *(const bf16x8*)(pn + kc * 32);
            }
        }

        // ---- D) recurrent K-loop: A from regs (tA), B from LDS Wh ----
#pragma unroll
        for (int kc = 0; kc < 24; ++kc) {
            int c8 = kc * 4 + kg;
#pragma unroll
            for (int nt = 0; nt < 3; ++nt) {
                int n = nt * 16 + m;
                bf16x8 b = *(const bf16x8*)(&Wh[n * HID + ((c8 ^ (n & 7)) << 3)]);
                acc[nt] = __builtin_amdgcn_mfma_f32_16x16x32_bf16(tA[kc], b, acc[nt], 0, 0, 0);
            }
        }

        // ---- E) gates -> wave-private LDS tile (no block sync needed) ----
#pragma unroll
        for (int nt = 0; nt < 3; ++nt) {
            int pl = nt * 16 + m;
#pragma unroll
            for (int r = 0; r < 4; ++r)
                gates[(v * 16 + kg * 4 + r) * GS + pl] = acc[nt][r];
        }

        // ---- F) wave-local LSTM cell update (lane owns window w_l, dims db..db+2) ----
        {
            const float* gr = &gates[w_l * GS + db];
            float hv[3];
#pragma unroll
            for (int e = 0; e < 3; ++e) {
                float ig = gr[e]          + bF[0][e];
                float fg = gr[SH + e]     + bF[1][e];
                float gg = gr[2 * SH + e] + bF[2][e];
                float og = gr[3 * SH + e] + bF[3][e];
                float c = sigm(fg) * cs[e] + sigm(ig) * tanhf(gg);
                cs[e] = c;
                hv[e] = sigm(og) * tanhf(c);
            }
            if (fvalid) {
                u16* hd = hist + ((size_t)(t + 1) * NW + GW * g + w_l) * HID + s * SH + db;
#pragma unroll
                for (int e = 0; e < 3; ++e)
                    __hip_atomic_store(hd + e, f2bf(hv[e]),
                                       __ATOMIC_RELAXED, __HIP_MEMORY_SCOPE_AGENT);
            }
        }

        if (t != TS - 1) flag_barrier(flg, s, t + 2);
    }
}

// ---------------- output head ----------------
__global__ void out_y(const u16* __restrict__ hist, const float* __restrict__ wout,
                      const float* __restrict__ bout, float* __restrict__ yn) {
    __shared__ float hv[HID];
    __shared__ float red[256];
    const int w = blockIdx.x, tid = threadIdx.x;
    for (int i = tid; i < HID; i += 256)
        hv[i] = bf2f(hist[((size_t)TS * NW + w) * HID + i]);
    __syncthreads();
    float acc = bout[tid];
    const float* wr = wout + (size_t)tid * HID;
    for (int k = 0; k < HID; ++k) acc += hv[k] * wr[k];
    red[tid] = acc * acc;
    __syncthreads();
    for (int off = 128; off > 0; off >>= 1) {
        if (tid < off) red[tid] += red[tid + off];
        __syncthreads();
    }
    float inv = 1.f / sqrtf(red[0]);
    yn[w * 256 + tid] = acc * inv;
}

__global__ void out_reduce(const float* __restrict__ yn, float* __restrict__ out) {
    const int o = threadIdx.x;
    float s = 0.f;
    for (int w = 0; w < NW; ++w) s += yn[w * 256 + o];
    out[o] = s * (1.f / NW);
}

// ---------------- host ----------------
extern "C" void kernel_launch(void* const* d_in, const int* in_sizes, int n_in,
                              void* d_out, int out_size, void* d_ws, size_t ws_size,
                              hipStream_t stream) {
    (void)in_sizes; (void)n_in; (void)out_size;
    const float* x    = (const float*)d_in[0];
    const float* wih0 = (const float*)d_in[1];
    const float* whh0 = (const float*)d_in[2];
    const float* bi0  = (const float*)d_in[3];
    const float* bh0  = (const float*)d_in[4];
    const float* wih1 = (const float*)d_in[5];
    const float* whh1 = (const float*)d_in[6];
    const float* bi1  = (const float*)d_in[7];
    const float* bh1  = (const float*)d_in[8];
    const float* wih2 = (const float*)d_in[9];
    const float* whh2 = (const float*)d_in[10];
    const float* bi2  = (const float*)d_in[11];
    const float* bh2  = (const float*)d_in[12];
    const float* wout = (const float*)d_in[13];
    const float* bout = (const float*)d_in[14];

    char* base = (char*)d_ws;
    size_t off = 0;
    auto take = [&](size_t bytes) { size_t r = off; off += (bytes + 255) & ~(size_t)255; return r; };
    u16*   HA  = (u16*)(base + take((size_t)(TS + 1) * NW * HID * 2)); // 49.5 MB
    u16*   HB  = (u16*)(base + take((size_t)(TS + 1) * NW * HID * 2)); // 49.5 MB
    int*   FLG = (int*)(base + take(768UL * 4));   // 3 layers x 4 groups x 64 flags
    float* YN  = (float*)(base + take((size_t)NW * 256 * 4));
    if (ws_size < off) return;  // ~99 MB needed; leave d_out zeroed (visible failure)

    zero_flags<<<dim3(3), dim3(256), 0, stream>>>(FLG);

    lstm_scan<0><<<dim3(256), dim3(256), 0, stream>>>(whh0, wih0, bi0, bh0, nullptr, x, HA, FLG);
    lstm_scan<1><<<dim3(256), dim3(256), 0, stream>>>(whh1, wih1, bi1, bh1, HA, nullptr, HB, FLG + 256);
    lstm_scan<2><<<dim3(256), dim3(256), 0, stream>>>(whh2, wih2, bi2, bh2, HB, nullptr, HA, FLG + 512);

    out_y<<<dim3(NW), dim3(256), 0, stream>>>(HA, wout, bout, YN);
    out_reduce<<<dim3(1), dim3(256), 0, stream>>>(YN, (float*)d_out);
}

// Round 8
// 4160.401 us; speedup vs baseline: 1.5894x; 1.2600x over previous
//
#include <hip/hip_runtime.h>
#include <cstdint>
#include <cstddef>

#define INP  40
#define HID  768
#define NG   3072      // 4*HID
#define NW   200       // windows
#define TS   160       // timesteps per window
#define GW   25        // windows per group (8 XCD-local groups)
#define SH   24        // h-dims per slice (32 slices)
#define SR   96        // gate rows per slice (4*SH)
#define GS   100       // gates LDS row stride (floats)

typedef __bf16 bf16x8 __attribute__((ext_vector_type(8)));
typedef float  f32x4  __attribute__((ext_vector_type(4)));
typedef unsigned short u16;
typedef unsigned int u32;

__device__ __forceinline__ u16 f2bf(float f) {
    unsigned u = __builtin_bit_cast(unsigned, f);
    unsigned r = ((u >> 16) & 1u) + 0x7fffu;   // RNE
    return (u16)((u + r) >> 16);
}
__device__ __forceinline__ float bf2f(u16 h) {
    unsigned u = ((unsigned)h) << 16;
    return __builtin_bit_cast(float, u);
}
__device__ __forceinline__ float sigm(float x) { return 1.f / (1.f + expf(-x)); }

// L1-bypass (sc0) load: reads the XCD's L2 — required for flag polling in L2-mode.
__device__ __forceinline__ int ld_sc0(const int* p) {
    int v;
    asm volatile("global_load_dword %0, %1, off sc0\n\ts_waitcnt vmcnt(0)"
                 : "=v"(v) : "v"(p) : "memory");
    return v;
}

// flags layout per layer (320 ints): [0..255] flags (g*32+s), [256] scream
__global__ void zero_flags(int* __restrict__ c) {
    int gid = blockIdx.x * 256 + threadIdx.x;            // 960 used
    if (gid < 960) c[gid] = ((gid % 320) < 256) ? -1 : 0;
}

// pre-pack W_ih layers 1,2 to bf16 in packed-slice row order: [layer][s*96+n][768]
__global__ void pack_wip(const float* __restrict__ w1, const float* __restrict__ w2,
                         u16* __restrict__ dst) {
    int gid = blockIdx.x * 256 + threadIdx.x;            // 2*NG*HID
    int l = gid / (NG * HID);
    int rem = gid - l * (NG * HID);
    int p = rem / HID, k = rem - p * HID;
    int s = p / SR, n = p - s * SR;
    int orow = (n / SH) * HID + s * SH + (n % SH);
    const float* w = l ? w2 : w1;
    dst[gid] = f2bf(w[(size_t)orow * HID + k]);
}

// ---------------- persistent recurrent scan, XCD-local groups ----------------
// grid 256 = 8 groups (g = bid&7, intended XCD-local) x 32 slices (s = bid>>3).
// block 256 = 4 waves: mt = v>>1 selects M-tile (windows mt*16.., valid<25),
// nb = (v&1)*48 selects N-half of the 96 gate cols.
template <int LAYER>
__launch_bounds__(256, 1)
__global__ void lstm_scan(const float* __restrict__ whh,   // [3072][768] fp32
                          const float* __restrict__ wih,   // layer0: [3072][40] fp32
                          const u16*  __restrict__ wip,    // layers1,2: packed bf16 [3072][768]
                          const float* __restrict__ b_ih,  // [3072]
                          const float* __restrict__ b_hh,  // [3072]
                          const u16*  __restrict__ prev,   // prev-layer hist (layers 1,2)
                          const float* __restrict__ x,     // raw input (layer 0)
                          u16* __restrict__ hist,          // [TS+1][NW][HID] bf16
                          int* __restrict__ flags)         // this layer's 320 ints
{
    __shared__ __align__(16) u16 Wh[SR * HID];       // 147456 B, swizzled
    __shared__ __align__(16) float gates[32 * GS];   // 12800 B  (total 160256 <= 163840)

    const int tid  = threadIdx.x;
    const int bid  = blockIdx.x;
    const int g    = bid & 7;
    const int s    = bid >> 3;
    const int v    = tid >> 6;
    const int lane = tid & 63;
    const int m    = lane & 15;
    const int kg   = lane >> 4;
    const int mt   = v >> 1;
    const int nb   = (v & 1) * 48;
    const int wl_f = mt * 16 + m;                        // valid < 25
    const int w_f  = GW * g + wl_f;
    const int w_c  = GW * g + ((wl_f < GW) ? wl_f : (GW - 1)); // group-local clamp
    int* flg    = flags + g * 32;
    int* scream = flags + 256;

    // ---- stage W_hh slice into LDS, fp32 -> bf16, XOR swizzle ----
    for (int idx = tid; idx < SR * (HID / 8); idx += 256) {
        int n = idx / (HID / 8), c8 = idx - n * (HID / 8);
        int orow = (n / SH) * HID + s * SH + (n % SH);
        const float* ph = whh + (size_t)orow * HID + c8 * 8;
        bf16x8 vh;
#pragma unroll
        for (int e = 0; e < 8; ++e) vh[e] = (__bf16)ph[e];
        *(bf16x8*)(&Wh[n * HID + ((c8 ^ (n & 7)) << 3)]) = vh;
    }

    // ---- elementwise items: i = tid + k*256 (k<3, i<600): window i/24, dim i%24 ----
    float bF[3][4];
    float cs[3] = {0.f, 0.f, 0.f};
#pragma unroll
    for (int k = 0; k < 3; ++k) {
        int i = tid + k * 256;
        if (i < GW * SH) {
            int d = i % SH, hd = s * SH + d;
#pragma unroll
            for (int q = 0; q < 4; ++q)
                bF[k][q] = b_ih[q * HID + hd] + b_hh[q * HID + hd];
        }
    }

    // layer-0: persistent W_ih fragments in registers (K = 40 padded to 64)
    bf16x8 bih[3][2];
    if constexpr (LAYER == 0) {
#pragma unroll
        for (int nt = 0; nt < 3; ++nt) {
            int pl = nb + nt * 16 + m;
            int orow = (pl / SH) * HID + s * SH + (pl % SH);
#pragma unroll
            for (int e = 0; e < 8; ++e) {
                int k0 = kg * 8 + e;
                int k1 = 32 + kg * 8 + e;
                bih[nt][0][e] = (k0 < INP) ? (__bf16)wih[(size_t)orow * INP + k0] : (__bf16)0.f;
                bih[nt][1][e] = (k1 < INP) ? (__bf16)wih[(size_t)orow * INP + k1] : (__bf16)0.f;
            }
        }
    }

    // ---- XCD identity check: scream if group is not XCD-pure ----
    {
        unsigned xcc = __builtin_amdgcn_s_getreg((3 << 11) | 20);  // HW_REG_XCC_ID, size 4
        if (tid == 0 && (int)(xcc & 7) != g)
            __hip_atomic_store(scream, 1, __ATOMIC_RELAXED, __HIP_MEMORY_SCOPE_AGENT);
    }

    // ---- zero own rows of hist slot 0 (UC stores: mode-independent correct) ----
#pragma unroll
    for (int k = 0; k < 3; ++k) {
        int i = tid + k * 256;
        if (i < GW * SH) {
            int w = i / SH, d = i - w * SH;
            __hip_atomic_store(hist + (size_t)(GW * g + w) * HID + s * SH + d, (u16)0,
                               __ATOMIC_RELAXED, __HIP_MEMORY_SCOPE_AGENT);
        }
    }

    __syncthreads();   // drain scream + slot-0 zeros
    if (tid == 0)
        __hip_atomic_store(flg + s, 0, __ATOMIC_RELAXED, __HIP_MEMORY_SCOPE_AGENT);

    // ---- one-time GLOBAL startup barrier (UC): all 256 flags >= 0 ----
    if (tid < 64) {
        while (true) {
            bool ok = true;
#pragma unroll
            for (int j = 0; j < 4; ++j)
                ok &= (__hip_atomic_load(flags + tid + j * 64, __ATOMIC_RELAXED,
                                         __HIP_MEMORY_SCOPE_AGENT) >= 0);
            if (__all(ok)) break;
            __builtin_amdgcn_s_sleep(1);
        }
    }
    __syncthreads();
    const bool uc = (__hip_atomic_load(scream, __ATOMIC_RELAXED,
                                       __HIP_MEMORY_SCOPE_AGENT) != 0);

    // prev-layer A-frag prefetch (slot 1), cached (immutable this dispatch)
    bf16x8 pf[24];
    const u16* wfr[3];
    if constexpr (LAYER != 0) {
        const u16* pr = prev + ((size_t)NW + w_c) * HID + kg * 8;
#pragma unroll
        for (int kc = 0; kc < 24; ++kc) pf[kc] = *(const bf16x8*)(pr + kc * 32);
#pragma unroll
        for (int nt = 0; nt < 3; ++nt)
            wfr[nt] = wip + (size_t)(s * SR + nb + nt * 16 + m) * HID + kg * 8;
    }
    const float* xr = x + (size_t)(80 * w_f) * INP;   // layer 0

    for (int t = 0; t < TS; ++t) {
        f32x4 acc[3];
        const f32x4 zf = {0.f, 0.f, 0.f, 0.f};
#pragma unroll
        for (int nt = 0; nt < 3; ++nt) acc[nt] = zf;

        // ---- pre-barrier phase: x-proj / Wi MFMAs (no dependence on own h(t-1)) ----
        if constexpr (LAYER == 0) {
            bf16x8 ax0 = (bf16x8)(__bf16)0.f, ax1 = (bf16x8)(__bf16)0.f;
            if (wl_f < GW) {
                const float4* p0 = (const float4*)(xr + kg * 8);
                float4 u0 = p0[0], u1 = p0[1];
                ax0[0] = (__bf16)u0.x; ax0[1] = (__bf16)u0.y; ax0[2] = (__bf16)u0.z; ax0[3] = (__bf16)u0.w;
                ax0[4] = (__bf16)u1.x; ax0[5] = (__bf16)u1.y; ax0[6] = (__bf16)u1.z; ax0[7] = (__bf16)u1.w;
                if (kg == 0) {
                    const float4* p1 = (const float4*)(xr + 32);
                    float4 q0 = p1[0], q1 = p1[1];
                    ax1[0] = (__bf16)q0.x; ax1[1] = (__bf16)q0.y; ax1[2] = (__bf16)q0.z; ax1[3] = (__bf16)q0.w;
                    ax1[4] = (__bf16)q1.x; ax1[5] = (__bf16)q1.y; ax1[6] = (__bf16)q1.z; ax1[7] = (__bf16)q1.w;
                }
            }
#pragma unroll
            for (int nt = 0; nt < 3; ++nt) {
                acc[nt] = __builtin_amdgcn_mfma_f32_16x16x32_bf16(ax0, bih[nt][0], acc[nt], 0, 0, 0);
                acc[nt] = __builtin_amdgcn_mfma_f32_16x16x32_bf16(ax1, bih[nt][1], acc[nt], 0, 0, 0);
            }
            xr += INP;
        } else {
            // h_prev(t) @ W_ih^T : A from prefetched regs, B streamed from L2 (packed bf16)
#pragma unroll
            for (int kc = 0; kc < 24; ++kc) {
                int off = kc * 32;
#pragma unroll
                for (int nt = 0; nt < 3; ++nt) {
                    bf16x8 b = *(const bf16x8*)(wfr[nt] + off);
                    acc[nt] = __builtin_amdgcn_mfma_f32_16x16x32_bf16(pf[kc], b, acc[nt], 0, 0, 0);
                }
            }
            if (t != TS - 1) {   // prefetch next step's prev frags (immutable)
                const u16* pn = prev + ((size_t)(t + 2) * NW + w_c) * HID + kg * 8;
#pragma unroll
                for (int kc = 0; kc < 24; ++kc) pf[kc] = *(const bf16x8*)(pn + kc * 32);
            }
        }

        // ---- wait for own-group h(t-1): flags >= t ----
        if (t > 0) {
            if (tid < 64) {
                const int* fp = flg + ((tid < 32) ? tid : 0);
                while (true) {
                    int f = uc ? __hip_atomic_load(fp, __ATOMIC_RELAXED, __HIP_MEMORY_SCOPE_AGENT)
                               : ld_sc0(fp);
                    if (__all(f >= t)) break;
                    __builtin_amdgcn_s_sleep(1);
                }
            }
            __syncthreads();
        }

        // ---- A-loads: own h slot t (L2-hit in L2-mode; cold lines, L1-safe) ----
        bf16x8 tA[24];
        const u16* hrow = hist + ((size_t)t * NW + w_c) * HID + kg * 8;
#pragma unroll
        for (int kc = 0; kc < 24; ++kc)
            tA[kc] = *(const bf16x8*)(hrow + kc * 32);

        // ---- recurrent K-loop: A regs, B from LDS Wh ----
#pragma unroll
        for (int kc = 0; kc < 24; ++kc) {
            int c8 = kc * 4 + kg;
#pragma unroll
            for (int nt = 0; nt < 3; ++nt) {
                int n = nb + nt * 16 + m;
                bf16x8 b = *(const bf16x8*)(&Wh[n * HID + ((c8 ^ (n & 7)) << 3)]);
                acc[nt] = __builtin_amdgcn_mfma_f32_16x16x32_bf16(tA[kc], b, acc[nt], 0, 0, 0);
            }
        }

        // ---- gates -> LDS (row = window 0..31, col = packed gate row 0..95) ----
#pragma unroll
        for (int nt = 0; nt < 3; ++nt) {
            int pl = nb + nt * 16 + m;
#pragma unroll
            for (int r = 0; r < 4; ++r)
                gates[(mt * 16 + kg * 4 + r) * GS + pl] = acc[nt][r];
        }
        __syncthreads();

        // ---- elementwise LSTM cell update (600 items), h-store per mode ----
#pragma unroll
        for (int k = 0; k < 3; ++k) {
            int i = tid + k * 256;
            if (i < GW * SH) {
                int w = i / SH, d = i - w * SH;
                const float* gr = &gates[w * GS + d];
                float ig = gr[0]      + bF[k][0];
                float fg = gr[SH]     + bF[k][1];
                float gg = gr[2 * SH] + bF[k][2];
                float og = gr[3 * SH] + bF[k][3];
                float c = sigm(fg) * cs[k] + sigm(ig) * tanhf(gg);
                cs[k] = c;
                u16 hb = f2bf(sigm(og) * tanhf(c));
                u16* hd = hist + ((size_t)(t + 1) * NW + GW * g + w) * HID + s * SH + d;
                if (uc) __hip_atomic_store(hd, hb, __ATOMIC_RELAXED, __HIP_MEMORY_SCOPE_AGENT);
                else    *hd = hb;
            }
        }
        __syncthreads();   // drain all waves' h-stores (ack at L2/DRAM) before arrival
        if (tid == 0 && t != TS - 1) {
            if (uc) __hip_atomic_store(flg + s, t + 1, __ATOMIC_RELAXED, __HIP_MEMORY_SCOPE_AGENT);
            else    { flg[s] = t + 1; asm volatile("" ::: "memory"); }
        }
    }
}

// ---------------- output head ----------------
__global__ void out_y(const u16* __restrict__ hist, const float* __restrict__ wout,
                      const float* __restrict__ bout, float* __restrict__ yn) {
    __shared__ float hv[HID];
    __shared__ float red[256];
    const int w = blockIdx.x, tid = threadIdx.x;
    for (int i = tid; i < HID; i += 256)
        hv[i] = bf2f(hist[((size_t)TS * NW + w) * HID + i]);
    __syncthreads();
    float acc = bout[tid];
    const float* wr = wout + (size_t)tid * HID;
    for (int k = 0; k < HID; ++k) acc += hv[k] * wr[k];
    red[tid] = acc * acc;
    __syncthreads();
    for (int off = 128; off > 0; off >>= 1) {
        if (tid < off) red[tid] += red[tid + off];
        __syncthreads();
    }
    float inv = 1.f / sqrtf(red[0]);
    yn[w * 256 + tid] = acc * inv;
}

__global__ void out_reduce(const float* __restrict__ yn, float* __restrict__ out) {
    const int o = threadIdx.x;
    float s = 0.f;
    for (int w = 0; w < NW; ++w) s += yn[w * 256 + o];
    out[o] = s * (1.f / NW);
}

// ---------------- host ----------------
extern "C" void kernel_launch(void* const* d_in, const int* in_sizes, int n_in,
                              void* d_out, int out_size, void* d_ws, size_t ws_size,
                              hipStream_t stream) {
    (void)in_sizes; (void)n_in; (void)out_size;
    const float* x    = (const float*)d_in[0];
    const float* wih0 = (const float*)d_in[1];
    const float* whh0 = (const float*)d_in[2];
    const float* bi0  = (const float*)d_in[3];
    const float* bh0  = (const float*)d_in[4];
    const float* wih1 = (const float*)d_in[5];
    const float* whh1 = (const float*)d_in[6];
    const float* bi1  = (const float*)d_in[7];
    const float* bh1  = (const float*)d_in[8];
    const float* wih2 = (const float*)d_in[9];
    const float* whh2 = (const float*)d_in[10];
    const float* bi2  = (const float*)d_in[11];
    const float* bh2  = (const float*)d_in[12];
    const float* wout = (const float*)d_in[13];
    const float* bout = (const float*)d_in[14];

    char* base = (char*)d_ws;
    size_t off = 0;
    auto take = [&](size_t bytes) { size_t r = off; off += (bytes + 255) & ~(size_t)255; return r; };
    u16*   HA  = (u16*)(base + take((size_t)(TS + 1) * NW * HID * 2)); // 49.5 MB
    u16*   HB  = (u16*)(base + take((size_t)(TS + 1) * NW * HID * 2)); // 49.5 MB
    u16*   WIP = (u16*)(base + take(2UL * NG * HID * 2));              // 9.4 MB
    int*   FLG = (int*)(base + take(3UL * 320 * 4));   // per-layer flags+scream
    float* YN  = (float*)(base + take((size_t)NW * 256 * 4));
    if (ws_size < off) return;  // ~109 MB needed; leave d_out zeroed (visible failure)

    zero_flags<<<dim3(4), dim3(256), 0, stream>>>(FLG);
    pack_wip<<<dim3(18432), dim3(256), 0, stream>>>(wih1, wih2, WIP);

    lstm_scan<0><<<dim3(256), dim3(256), 0, stream>>>(whh0, wih0, nullptr, bi0, bh0,
                                                      nullptr, x, HA, FLG);
    lstm_scan<1><<<dim3(256), dim3(256), 0, stream>>>(whh1, nullptr, WIP, bi1, bh1,
                                                      HA, nullptr, HB, FLG + 320);
    lstm_scan<2><<<dim3(256), dim3(256), 0, stream>>>(whh2, nullptr, WIP + (size_t)NG * HID,
                                                      bi2, bh2, HB, nullptr, HA, FLG + 640);

    out_y<<<dim3(NW), dim3(256), 0, stream>>>(HA, wout, bout, YN);
    out_reduce<<<dim3(1), dim3(256), 0, stream>>>(YN, (float*)d_out);
}